// Round 2
// baseline (3996.997 us; speedup 1.0000x reference)
//
#include <hip/hip_runtime.h>
#include <math.h>

#define BB 32768
#define BN 20
#define DD 172
#define TT 100
#define EE 272
#define HD2 136
#define BT 8

// Tiled mat-vec batch: OUT[i][e] = act(bias[e] + sum_k A[i][k] * W[e*ldw + kcol0 + k])
// 256 threads: lane eo=t&63 handles e in {eo, eo+64, ...} paired 2 at a time;
// group t>>6 handles 2 batch rows.
__device__ __forceinline__ void gemm_rowW(
    const float* __restrict__ W, int ldw, int kcol0,
    const float* __restrict__ bias,          // may be null
    const float* __restrict__ A, int lda,    // A[i*lda + k]; lda==0 -> broadcast row
    int K,
    float* OUT, int ldo, int NO,
    bool accum, int act,                     // 0 none, 1 relu, 2 zero-if-invalid
    const int* __restrict__ inval,
    float* __restrict__ gout, int gld,       // if non-null write here instead
    int t)
{
  const int eo = t & 63;
  const int i0 = (t >> 6) * 2;
  for (int e = eo; e < NO; e += 128) {
    const int e2 = e + 64;
    const bool has2 = (e2 < NO);
    float acc[2][2];
    const float b1 = (!accum && bias) ? bias[e] : 0.f;
    const float b2 = (!accum && bias && has2) ? bias[e2] : 0.f;
#pragma unroll
    for (int ii = 0; ii < 2; ii++) {
      acc[ii][0] = accum ? OUT[(i0 + ii) * ldo + e] : b1;
      acc[ii][1] = has2 ? (accum ? OUT[(i0 + ii) * ldo + e2] : b2) : 0.f;
    }
    const float* w1 = W + (size_t)e * ldw + kcol0;
    const float* w2 = W + (size_t)e2 * ldw + kcol0;
    for (int k = 0; k < K; k += 4) {
      const float4 wq1 = *(const float4*)(w1 + k);
      float4 wq2 = make_float4(0.f, 0.f, 0.f, 0.f);
      if (has2) wq2 = *(const float4*)(w2 + k);
#pragma unroll
      for (int ii = 0; ii < 2; ii++) {
        const float4 a = *(const float4*)(A + (size_t)(i0 + ii) * lda + k);
        acc[ii][0] += a.x * wq1.x + a.y * wq1.y + a.z * wq1.z + a.w * wq1.w;
        acc[ii][1] += a.x * wq2.x + a.y * wq2.y + a.z * wq2.z + a.w * wq2.w;
      }
    }
#pragma unroll
    for (int ii = 0; ii < 2; ii++) {
      float v1 = acc[ii][0], v2 = acc[ii][1];
      if (act == 1) { v1 = fmaxf(v1, 0.f); v2 = fmaxf(v2, 0.f); }
      else if (act == 2) { if (inval[i0 + ii]) { v1 = 0.f; v2 = 0.f; } }
      if (gout) {
        gout[(i0 + ii) * gld + e] = v1;
        if (has2) gout[(i0 + ii) * gld + e2] = v2;
      } else {
        OUT[(i0 + ii) * ldo + e] = v1;
        if (has2) OUT[(i0 + ii) * ldo + e2] = v2;
      }
    }
  }
}

// Column variant: OUT[i][j] = sum_d A[i][d] * W[d*ldw + j]; lanes j consecutive
// -> coalesced weight reads.
__device__ __forceinline__ void gemm_colW(
    const float* __restrict__ W, int ldw,
    const float* __restrict__ A, int lda,
    int K,
    float* OUT, int ldo, int NO,
    int t)
{
  const int eo = t & 63;
  const int i0 = (t >> 6) * 2;
  for (int j = eo; j < NO; j += 128) {
    const int j2 = j + 64;
    const bool has2 = (j2 < NO);
    float acc[2][2];
#pragma unroll
    for (int ii = 0; ii < 2; ii++) { acc[ii][0] = 0.f; acc[ii][1] = 0.f; }
    for (int d = 0; d < K; d += 4) {
      const float* wr = W + (size_t)d * ldw;
      const float w10 = wr[j];
      const float w11 = wr[ldw + j];
      const float w12 = wr[2 * ldw + j];
      const float w13 = wr[3 * ldw + j];
      float w20 = 0.f, w21 = 0.f, w22 = 0.f, w23 = 0.f;
      if (has2) { w20 = wr[j2]; w21 = wr[ldw + j2]; w22 = wr[2 * ldw + j2]; w23 = wr[3 * ldw + j2]; }
#pragma unroll
      for (int ii = 0; ii < 2; ii++) {
        const float4 a = *(const float4*)(A + (size_t)(i0 + ii) * lda + d);
        acc[ii][0] += a.x * w10 + a.y * w11 + a.z * w12 + a.w * w13;
        acc[ii][1] += a.x * w20 + a.y * w21 + a.z * w22 + a.w * w23;
      }
    }
#pragma unroll
    for (int ii = 0; ii < 2; ii++) {
      OUT[(i0 + ii) * ldo + j] = acc[ii][0];
      if (has2) OUT[(i0 + ii) * ldo + j2] = acc[ii][1];
    }
  }
}

__global__ __launch_bounds__(256, 4)
void attn_msg_agg_fused(const float* __restrict__ msg,
                        const float* __restrict__ timeb,
                        const float* __restrict__ tw_g,
                        const float* __restrict__ tb_g,
                        const float* __restrict__ ipw,
                        const float* __restrict__ ipb,
                        const float* __restrict__ opw,
                        const float* __restrict__ opb,
                        const float* __restrict__ f1w,
                        const float* __restrict__ f1b,
                        const float* __restrict__ f2w,
                        const float* __restrict__ f2b,
                        float* __restrict__ outg)
{
  __shared__ __align__(16) float s_q[BT * EE];          // q -> ctx -> h1      (8.7 KB)
  __shared__ __align__(16) float s_qk[BT * 2 * EE];     // qk -> mbar -> attn_out (17.4 KB)
  __shared__ __align__(16) float s_src[BT * DD];        // source row          (5.5 KB)
  __shared__ __align__(16) float s_attn[BT * 2 * BN];
  __shared__ __align__(16) float s_delta[BT * BN];
  __shared__ __align__(16) float s_tw[TT];
  __shared__ __align__(16) float s_tb[TT];
  __shared__ __align__(16) float s_tfl[TT];
  __shared__ float s_sconst[BT * 2];
  __shared__ unsigned s_mask[BT];
  __shared__ int s_inval[BT];

  const int t = threadIdx.x;
  const int base = blockIdx.x * BT;

  // ---- P0: time consts, delta/mask, stage source rows ----
  if (t < TT) {
    const float b = tb_g[t];
    s_tw[t] = tw_g[t];
    s_tb[t] = b;
    s_tfl[t] = __cosf(b);          // time feature at n=N-1 (delta=0)
  }
  for (int idx = t; idx < BT * BN; idx += 256)
    s_delta[idx] = timeb[(size_t)base * BN + idx];
  for (int idx = t; idx < BT * DD; idx += 256) {
    const int i = idx / DD, j = idx % DD;
    s_src[idx] = msg[((size_t)(base + i) * BN + (BN - 1)) * DD + j];
  }
  __syncthreads();
  if (t < BT) {
    const float st = s_delta[t * BN + BN - 1];
    unsigned m = 0;
#pragma unroll
    for (int n = 0; n < BN; n++) {
      const float v = s_delta[t * BN + n];
      if (v < 0.f) m |= (1u << n);
      s_delta[t * BN + n] = v - st;
    }
    const int inv = (m == ((1u << BN) - 1u)) ? 1 : 0;
    if (inv) m &= ~1u;             // mask[0] forced False when all-masked
    s_mask[t] = m;
    s_inval[t] = inv;
  }
  __syncthreads();

  // ---- P1: q = [source, tf_last] @ Wq^T + bq ----
  gemm_rowW(ipw, EE, 0, ipb, s_src, DD, DD, s_q, EE, EE, false, 0, nullptr, nullptr, 0, t);
  gemm_rowW(ipw, EE, DD, nullptr, s_tfl, 0, TT, s_q, EE, EE, true, 0, nullptr, nullptr, 0, t);
  __syncthreads();

  // ---- P2: qk[h] = q[h] @ Wk_h (fold q into Wk), sconst[h] = q[h].bk_h ----
  if (t < BT * 2) {
    const int i = t >> 1, h = t & 1;
    const float* qv = s_q + i * EE + h * HD2;
    const float* bk = ipb + EE + h * HD2;
    float s = 0.f;
    for (int d = 0; d < HD2; d++) s += qv[d] * bk[d];
    s_sconst[t] = s;
  }
  gemm_colW(ipw + (size_t)EE * EE, EE, s_q, EE, HD2, s_qk, 2 * EE, EE, t);
  gemm_colW(ipw + (size_t)(EE + HD2) * EE, EE, s_q + HD2, EE, HD2, s_qk + EE, 2 * EE, EE, t);
  __syncthreads();

  // ---- P3: scores for both heads together (shared msg reads + shared cos) ----
  const float scale = 0.08574929257125442f;  // 1/sqrt(136)
  for (int o = t; o < BT * BN; o += 256) {
    const int i = o / BN;
    const int n = o % BN;
    const float* mrow = msg + ((size_t)(base + i) * BN + n) * DD;
    const float* qk0 = s_qk + i * 2 * EE;
    const float* qk1 = qk0 + EE;
    float s0 = s_sconst[i * 2];
    float s1 = s_sconst[i * 2 + 1];
    for (int d = 0; d < DD; d += 4) {
      const float4 m4 = *(const float4*)(mrow + d);
      const float4 q40 = *(const float4*)(qk0 + d);
      const float4 q41 = *(const float4*)(qk1 + d);
      s0 += m4.x * q40.x + m4.y * q40.y + m4.z * q40.z + m4.w * q40.w;
      s1 += m4.x * q41.x + m4.y * q41.y + m4.z * q41.z + m4.w * q41.w;
    }
    const float del = s_delta[i * BN + n];
    for (int u = 0; u < TT; u++) {
      const float c = __cosf(del * s_tw[u] + s_tb[u]);
      s0 += c * qk0[DD + u];
      s1 += c * qk1[DD + u];
    }
    const bool masked = (s_mask[i] >> n) & 1u;
    s_attn[(i * 2 + 0) * BN + n] = masked ? -1e9f : s0 * scale;
    s_attn[(i * 2 + 1) * BN + n] = masked ? -1e9f : s1 * scale;
  }
  __syncthreads();

  // ---- P3b: softmax over n per (i,h) ----
  if (t < BT * 2) {
    float* sc = s_attn + t * BN;
    float m = -3.4e38f;
#pragma unroll
    for (int n = 0; n < BN; n++) m = fmaxf(m, sc[n]);
    float sum = 0.f;
#pragma unroll
    for (int n = 0; n < BN; n++) { const float e = __expf(sc[n] - m); sc[n] = e; sum += e; }
    const float inv = 1.f / sum;
#pragma unroll
    for (int n = 0; n < BN; n++) sc[n] *= inv;
  }
  __syncthreads();

  // ---- P4: mbar[i][h][:] = attn-weighted mean message (overwrites qk) ----
  // D-part: coalesced msg column reads
  for (int o = t; o < BT * 2 * DD; o += 256) {
    const int i = o / (2 * DD);
    const int r = o % (2 * DD);
    const int h = r / DD;
    const int j = r % DD;
    const float* at = s_attn + (i * 2 + h) * BN;
    const float* mp = msg + (size_t)(base + i) * BN * DD + j;
    float acc = 0.f;
#pragma unroll
    for (int n = 0; n < BN; n++) acc += at[n] * mp[n * DD];
    s_qk[i * 2 * EE + h * EE + j] = acc;
  }
  // T-part: one cos shared across both heads
  for (int o = t; o < BT * TT; o += 256) {
    const int i = o / TT;
    const int u = o % TT;
    const float w = s_tw[u], b = s_tb[u];
    const float* at0 = s_attn + i * 2 * BN;
    const float* at1 = at0 + BN;
    float a0 = 0.f, a1 = 0.f;
#pragma unroll
    for (int n = 0; n < BN; n++) {
      const float c = __cosf(s_delta[i * BN + n] * w + b);
      a0 += at0[n] * c;
      a1 += at1[n] * c;
    }
    s_qk[i * 2 * EE + DD + u] = a0;
    s_qk[i * 2 * EE + EE + DD + u] = a1;
  }
  __syncthreads();

  // ---- P5: ctx[h] = mbar[h] @ Wv_h^T + bv_h ----
  gemm_rowW(ipw + (size_t)(2 * EE) * EE, EE, 0, ipb + 2 * EE,
            s_qk, 2 * EE, EE, s_q, EE, HD2, false, 0, nullptr, nullptr, 0, t);
  gemm_rowW(ipw + (size_t)(2 * EE + HD2) * EE, EE, 0, ipb + 2 * EE + HD2,
            s_qk + EE, 2 * EE, EE, s_q + HD2, EE, HD2, false, 0, nullptr, nullptr, 0, t);
  __syncthreads();

  // ---- P6: attn_out = ctx @ Wo^T + bo, zero if invalid -> s_qk ----
  gemm_rowW(opw, EE, 0, opb, s_q, EE, EE, s_qk, 2 * EE, EE, false, 2, s_inval, nullptr, 0, t);
  __syncthreads();

  // ---- P7: h1 = relu([attn_out, source] @ fc1^T + b1) -> s_q ----
  gemm_rowW(f1w, EE + DD, 0, f1b, s_qk, 2 * EE, EE, s_q, EE, DD, false, 0, nullptr, nullptr, 0, t);
  gemm_rowW(f1w, EE + DD, EE, nullptr, s_src, DD, DD, s_q, EE, DD, true, 1, nullptr, nullptr, 0, t);
  __syncthreads();

  // ---- P8: out = h1 @ fc2^T + b2 -> global ----
  gemm_rowW(f2w, DD, 0, f2b, s_q, EE, DD, nullptr, 0, DD, false, 0, nullptr,
            outg + (size_t)base * DD, DD, t);
}

extern "C" void kernel_launch(void* const* d_in, const int* in_sizes, int n_in,
                              void* d_out, int out_size, void* d_ws, size_t ws_size,
                              hipStream_t stream) {
  const float* msg  = (const float*)d_in[0];
  const float* tb   = (const float*)d_in[1];
  // d_in[2] (memory) is unused by the reference
  const float* tw_g = (const float*)d_in[3];
  const float* tb_g = (const float*)d_in[4];
  const float* ipw  = (const float*)d_in[5];
  const float* ipb  = (const float*)d_in[6];
  const float* opw  = (const float*)d_in[7];
  const float* opb  = (const float*)d_in[8];
  const float* f1w  = (const float*)d_in[9];
  const float* f1b  = (const float*)d_in[10];
  const float* f2w  = (const float*)d_in[11];
  const float* f2b  = (const float*)d_in[12];
  float* outg = (float*)d_out;

  dim3 grid(BB / BT), block(256);
  hipLaunchKernelGGL(attn_msg_agg_fused, grid, block, 0, stream,
                     msg, tb, tw_g, tb_g, ipw, ipb, opw, opb, f1w, f1b, f2w, f2b, outg);
}